// Round 8
// baseline (238.054 us; speedup 1.0000x reference)
//
#include <hip/hip_runtime.h>
#include <hip/hip_bf16.h>
#include <math.h>

// Problem constants (fixed by reference)
#define NN 100000   // nodes
#define FF 128      // features
#define DD 16       // degree
#define KK 8        // hashers
#define HH 256      // hash dim
#define OO 256      // out dim
#define KH 2048     // K*H
// C[NN,256] = A[NN,256](bf16) @ Bw[256,256](bf16), K = 2F = 256.
// A cols 0..127 = mean(neigh), 128..255 = self. Bw rows: 0..127 Wn-part, 128..255 Ws-part.
// R8: gather MLP x4 — all 32 dwordx2 neighbor loads (2 row-groups x 16) issued before
//     any decode; decode of group 0 overlaps group 1's in-flight loads (counted vmcnt).
//     R7 PMC: k_fused 73.5us @ 2.63 TB/s, VALUBusy 22%, MfmaUtil 7% -> MLP-bound
//     (8 loads in flight/wave sustains ~2.6 TB/s at ~700cyc latency). VGPR 36 -> ~100,
//     still under the (512,4) cap of 128. Numerics identical to R7 (absmax 0.75 passed;
//     no further precision reduction).

using frag_t  = __attribute__((ext_vector_type(8))) short;   // 8 bf16 = 4 VGPR (MFMA A/B frag)
using f32x4   = __attribute__((ext_vector_type(4))) float;   // MFMA C/D frag
using f32x2   = __attribute__((ext_vector_type(2))) float;
using ushort8 = __attribute__((ext_vector_type(8))) unsigned short;
using uv4     = __attribute__((ext_vector_type(4))) unsigned int;
using uv2     = __attribute__((ext_vector_type(2))) unsigned int;

static __device__ __forceinline__ unsigned short f2bf(float f) {
    union { float f; unsigned int i; } v; v.f = f;
    unsigned int x = v.i;
    x += 0x7fffu + ((x >> 16) & 1u);   // round-to-nearest-even
    return (unsigned short)(x >> 16);
}
static __device__ __forceinline__ unsigned int pk2(float a, float b) {
    return (unsigned int)f2bf(a) | ((unsigned int)f2bf(b) << 16);
}

// ---------------- FP8 (OCP e4m3fn) helpers: HW cvt if available, bit-exact fallback ----------------
#if defined(__has_builtin)
#if __has_builtin(__builtin_amdgcn_cvt_pk_f32_fp8) && __has_builtin(__builtin_amdgcn_cvt_pk_fp8_f32)
#define FP8_HW 1
#endif
#endif
#ifndef FP8_HW
#define FP8_HW 0
#endif

static __device__ __forceinline__ float e4m3f(unsigned int b) {   // fallback decode
    unsigned int s = (b & 0x80u) << 24;
    unsigned int em = b & 0x7fu;
    bool den = (b & 0x78u) == 0;                      // exp field == 0 -> denormal
    union { unsigned int u; float f; } v;
    v.u = s | ((em << 20) + ((den ? 121u : 120u) << 23));
    float f = v.f;
    if (den) f -= (s ? -0.015625f : 0.015625f);       // remove implicit-1 (2^-6)
    return f;
}
static __device__ __forceinline__ unsigned int f2e4m3(float f) {  // fallback encode (RNE)
    union { float f; unsigned int u; } v; v.f = f;
    unsigned int s = (v.u >> 24) & 0x80u;
    float a = fabsf(f);
    if (!(a < 448.f)) return s | 0x7Eu;               // clamp (also catches NaN)
    if (a < 0.015625f) {                              // denormal, quantum 2^-9
        int m = (int)rintf(a * 512.f);                // 0..8 (8 == e=1,m=0 bit pattern)
        return s | (unsigned int)m;
    }
    union { float f; unsigned int u; } w; w.f = a;
    unsigned int u = w.u + 0x7FFFFu + ((w.u >> 20) & 1u);   // RNE at bit 20
    return s | (((u >> 23) - 120u) << 3) | ((u >> 20) & 7u);
}
template <int SEL>   // SEL=0: bytes 0-1, SEL=1: bytes 2-3
static __device__ __forceinline__ f32x2 dec2(unsigned int w) {
#if FP8_HW
    return __builtin_amdgcn_cvt_pk_f32_fp8((int)w, SEL != 0);
#else
    f32x2 r;
    r[0] = e4m3f((w >> (SEL * 16)) & 0xffu);
    r[1] = e4m3f((w >> (SEL * 16 + 8)) & 0xffu);
    return r;
#endif
}
static __device__ __forceinline__ unsigned int enc4(float x0, float x1, float x2, float x3) {
#if FP8_HW
    int r = __builtin_amdgcn_cvt_pk_fp8_f32(x0, x1, 0, false);
    r = __builtin_amdgcn_cvt_pk_fp8_f32(x2, x3, r, true);
    return (unsigned int)r;
#else
    return f2e4m3(x0) | (f2e4m3(x1) << 8) | (f2e4m3(x2) << 16) | (f2e4m3(x3) << 24);
#endif
}

// ------- Kernel 1: prep = weight-MFMA (blocks 0..7) + x cast (blocks 8..3132) -------
// Weight block b (0..7): w=b>>2 (0=Wn,1=Ws), ot=b&3. Output Bbf[o][w*128+f] for
//   o in [ot*64,+64), f in [0,128): sum_j R[j>>8][f][j&255] * W[o][j], K=2048.
//   8 waves as 2(o)x4(f), wave tile 32x32, acc 2x2 frags 16x16x32. BK=64, 32 kt iters.
//   Register-prefetch pipeline: kt+1 global loads issued before the MFMA barrier.
// Cast blocks: 512 thr x 8 floats -> bf16 row (xb) + fp8 row (xb8).
__global__ __launch_bounds__(512) void k_prep(const float* __restrict__ x,
                                              const float* __restrict__ R,
                                              const float* __restrict__ Ws,
                                              const float* __restrict__ Wn,
                                              unsigned short* __restrict__ xb,
                                              unsigned char* __restrict__ xb8,
                                              unsigned short* __restrict__ Bbf) {
    __shared__ __align__(16) unsigned short Aw[64][72];    // W tile, bf16 ( 9.2 KB)
    __shared__ __align__(16) unsigned short Bw[128][72];   // R tile, bf16 (18.4 KB)
    int b = blockIdx.x;
    int t = threadIdx.x;
    if (b >= 8) {
        // ---- cast path ----
        int g = (b - 8) * 512 + t;
        const float4* xv = (const float4*)x;
        float4 a = xv[2 * g], c = xv[2 * g + 1];
        ushort8 o;
        o[0] = f2bf(a.x); o[1] = f2bf(a.y); o[2] = f2bf(a.z); o[3] = f2bf(a.w);
        o[4] = f2bf(c.x); o[5] = f2bf(c.y); o[6] = f2bf(c.z); o[7] = f2bf(c.w);
        *(ushort8*)(xb + (size_t)g * 8) = o;
        uv2 q;
        q.x = enc4(a.x, a.y, a.z, a.w);
        q.y = enc4(c.x, c.y, c.z, c.w);
        *(uv2*)(xb8 + (size_t)g * 8) = q;
        return;
    }
    // ---- weight MFMA path ----
    const int w = b >> 2, ot = b & 3;
    const float* W = (w == 0) ? Wn : Ws;
    int lane = t & 63, wv = t >> 6;
    int wo = wv >> 2, wf = wv & 3;            // 2(o) x 4(f) waves, 32x32 each
    int l15 = lane & 15, quad = lane >> 4;
    int rA[2], cA[2], rB[4], cB[4];
#pragma unroll
    for (int s = 0; s < 2; ++s) { int c0 = s * 512 + t; rA[s] = c0 >> 4; cA[s] = c0 & 15; }
#pragma unroll
    for (int s = 0; s < 4; ++s) { int c0 = s * 512 + t; rB[s] = c0 >> 4; cB[s] = c0 & 15; }
    float4 av[2], bv[4];
#pragma unroll
    for (int s = 0; s < 2; ++s)
        av[s] = *(const float4*)(W + (size_t)(ot * 64 + rA[s]) * KH + cA[s] * 4);
#pragma unroll
    for (int s = 0; s < 4; ++s)
        bv[s] = *(const float4*)(R + (size_t)rB[s] * 256 + cB[s] * 4);
    f32x4 acc[2][2] = {};
    for (int kt = 0; kt < 32; ++kt) {         // BK = 64
        __syncthreads();                      // prev iteration's frag reads done
#pragma unroll
        for (int s = 0; s < 2; ++s) {
            uint2 p; p.x = pk2(av[s].x, av[s].y); p.y = pk2(av[s].z, av[s].w);
            *(uint2*)&Aw[rA[s]][cA[s] * 4] = p;
        }
#pragma unroll
        for (int s = 0; s < 4; ++s) {
            uint2 p; p.x = pk2(bv[s].x, bv[s].y); p.y = pk2(bv[s].z, bv[s].w);
            *(uint2*)&Bw[rB[s]][cB[s] * 4] = p;
        }
        if (kt < 31) {                        // prefetch kt+1 (overlaps barrier+MFMA)
            int k1 = kt + 1;
#pragma unroll
            for (int s = 0; s < 2; ++s)
                av[s] = *(const float4*)(W + (size_t)(ot * 64 + rA[s]) * KH + k1 * 64 + cA[s] * 4);
#pragma unroll
            for (int s = 0; s < 4; ++s)
                bv[s] = *(const float4*)(R + (size_t)(k1 >> 2) * 32768
                                           + (size_t)rB[s] * 256 + (k1 & 3) * 64 + cB[s] * 4);
        }
        __syncthreads();
#pragma unroll
        for (int k2 = 0; k2 < 2; ++k2) {
            frag_t af[2], bfr[2];
#pragma unroll
            for (int i = 0; i < 2; ++i)
                af[i] = *(const frag_t*)&Aw[wo * 32 + i * 16 + l15][k2 * 32 + quad * 8];
#pragma unroll
            for (int j = 0; j < 2; ++j)
                bfr[j] = *(const frag_t*)&Bw[wf * 32 + j * 16 + l15][k2 * 32 + quad * 8];
#pragma unroll
            for (int i = 0; i < 2; ++i)
#pragma unroll
                for (int j = 0; j < 2; ++j)
                    acc[i][j] = __builtin_amdgcn_mfma_f32_16x16x32_bf16(af[i], bfr[j], acc[i][j], 0, 0, 0);
        }
    }
    // write Bbf[o][w*128+f]; C/D layout: col(n)=l15 -> f (R-row), row(m)=quad*4+r -> o (W-row)
#pragma unroll
    for (int j = 0; j < 2; ++j) {
        int f = wf * 32 + j * 16 + l15;
#pragma unroll
        for (int i = 0; i < 2; ++i) {
            int o0 = ot * 64 + wo * 32 + i * 16 + quad * 4;
#pragma unroll
            for (int r = 0; r < 4; ++r)
                Bbf[(size_t)(o0 + r) * 256 + w * 128 + f] = f2bf(acc[i][j][r]);
        }
    }
}

// --------- Kernel 2 (fused): fp8 gather-mean -> LDS A-tile -> MFMA GEMM + bias + ELU ---------
// BM=64 x BN=256, 512 threads = 8 waves, wave tile 64x32 (acc 4x2 frags).
// Gather (R8): lane=(r4,l16); BOTH row-groups' 16 dwordx2 loads issued back-to-back
//   (32 x 512B in flight per wave) before any decode; decode of group 0 overlaps
//   group 1's outstanding loads via counted vmcnt. Accumulation order per group
//   identical to R7 (bit-identical numerics). Mean in f32 -> bf16.
// Self row from xb (bf16) via nt-load; nbr via nt-load (single-use streams).
// LDS: Als[64][264] bf16 only (33.8 KB); B-frags straight from global (128 KB, L2-hot);
//   K-loop barrier-free. Epilogue: LDS-staged full-line nt float4 stores.
__global__ __launch_bounds__(512, 4) void k_fused(const unsigned short* __restrict__ xb,
                                                  const unsigned char* __restrict__ xb8,
                                                  const int* __restrict__ nbr,
                                                  const unsigned short* __restrict__ Bw,
                                                  const float* __restrict__ bias,
                                                  float* __restrict__ C) {
    __shared__ __align__(16) char smraw[64 * 264 * 2];   // 33792 B, dual-purpose
    unsigned short (*Als)[264] = (unsigned short (*)[264])smraw;
    float* Fls = (float*)smraw;                          // [32][260] floats (33280 B)
    const int FLS_W = 260;

    int m0 = blockIdx.x * 64;
    int t = threadIdx.x;
    int lane = t & 63, wv = t >> 6;           // 8 waves
    int l15 = lane & 15, quad = lane >> 4;
    int l16 = lane & 15, r4 = lane >> 4;      // gather mapping: 4 rows x 16 feature-lanes
    int selbase = (lane & 48) << 2;           // bpermute selector base (group start lane *4)

    // ---- gather phase: issue BOTH groups' loads, then decode both ----
    int row0 = wv * 8 + r4,     row1 = wv * 8 + 4 + r4;
    int node0 = m0 + row0; if (node0 >= NN) node0 = NN - 1;
    int node1 = m0 + row1; if (node1 >= NN) node1 = NN - 1;
    int myidx0 = __builtin_nontemporal_load(nbr + (size_t)node0 * 16 + l16);
    int myidx1 = __builtin_nontemporal_load(nbr + (size_t)node1 * 16 + l16);
    uv4 self0 = __builtin_nontemporal_load((const uv4*)(xb + (size_t)node0 * 128 + l16 * 8));
    uv4 self1 = __builtin_nontemporal_load((const uv4*)(xb + (size_t)node1 * 128 + l16 * 8));
    uv2 gv0[16], gv1[16];
#pragma unroll
    for (int d = 0; d < 16; ++d) {
        int bi = __builtin_amdgcn_ds_bpermute(selbase + (d << 2), myidx0);
        gv0[d] = *(const uv2*)(xb8 + (size_t)bi * 128 + l16 * 8);
    }
#pragma unroll
    for (int d = 0; d < 16; ++d) {
        int bi = __builtin_amdgcn_ds_bpermute(selbase + (d << 2), myidx1);
        gv1[d] = *(const uv2*)(xb8 + (size_t)bi * 128 + l16 * 8);
    }
    {   // decode group 0 (overlaps group 1 loads in flight)
        float s[8] = {0.f, 0.f, 0.f, 0.f, 0.f, 0.f, 0.f, 0.f};
#pragma unroll
        for (int d = 0; d < 16; ++d) {
            f32x2 p;
            p = dec2<0>(gv0[d].x); s[0] += p[0]; s[1] += p[1];
            p = dec2<1>(gv0[d].x); s[2] += p[0]; s[3] += p[1];
            p = dec2<0>(gv0[d].y); s[4] += p[0]; s[5] += p[1];
            p = dec2<1>(gv0[d].y); s[6] += p[0]; s[7] += p[1];
        }
        ushort8 o;
#pragma unroll
        for (int k = 0; k < 8; ++k) o[k] = f2bf(s[k] * 0.0625f);
        *(ushort8*)&Als[row0][l16 * 8] = o;               // mean features 0..127
        *(uv4*)&Als[row0][128 + l16 * 8] = self0;         // self features 128..255
    }
    {   // decode group 1
        float s[8] = {0.f, 0.f, 0.f, 0.f, 0.f, 0.f, 0.f, 0.f};
#pragma unroll
        for (int d = 0; d < 16; ++d) {
            f32x2 p;
            p = dec2<0>(gv1[d].x); s[0] += p[0]; s[1] += p[1];
            p = dec2<1>(gv1[d].x); s[2] += p[0]; s[3] += p[1];
            p = dec2<0>(gv1[d].y); s[4] += p[0]; s[5] += p[1];
            p = dec2<1>(gv1[d].y); s[6] += p[0]; s[7] += p[1];
        }
        ushort8 o;
#pragma unroll
        for (int k = 0; k < 8; ++k) o[k] = f2bf(s[k] * 0.0625f);
        *(ushort8*)&Als[row1][l16 * 8] = o;               // mean features 0..127
        *(uv4*)&Als[row1][128 + l16 * 8] = self1;         // self features 128..255
    }
    __syncthreads();

    // ---- K-loop: barrier-free; B-frags from global (L2-hot 128 KB)
    f32x4 acc[4][2] = {};
#pragma unroll 1
    for (int kt = 0; kt < 4; ++kt) {
#pragma unroll
        for (int k2 = 0; k2 < 2; ++k2) {
            frag_t bfr[2], af[4];
#pragma unroll
            for (int j = 0; j < 2; ++j)
                bfr[j] = *(const frag_t*)(Bw + (size_t)(wv * 32 + j * 16 + l15) * 256
                                             + kt * 64 + k2 * 32 + quad * 8);
#pragma unroll
            for (int i = 0; i < 4; ++i)
                af[i] = *(const frag_t*)&Als[i * 16 + l15][kt * 64 + k2 * 32 + quad * 8];
#pragma unroll
            for (int i = 0; i < 4; ++i)
#pragma unroll
                for (int j = 0; j < 2; ++j)
                    acc[i][j] = __builtin_amdgcn_mfma_f32_16x16x32_bf16(af[i], bfr[j], acc[i][j], 0, 0, 0);
        }
    }

    // ---- epilogue: bias+ELU in-reg, stage 32-row halves in LDS, full-line nt stores
    float bv[2];
#pragma unroll
    for (int j = 0; j < 2; ++j) bv[j] = bias[wv * 32 + j * 16 + l15];
#pragma unroll
    for (int p = 0; p < 2; ++p) {
        __syncthreads();     // p=0: Als frag reads done; p=1: prev pass reads done
#pragma unroll
        for (int ii = 0; ii < 2; ++ii) {
            int i = p * 2 + ii;
#pragma unroll
            for (int j = 0; j < 2; ++j) {
                int col = wv * 32 + j * 16 + l15;
#pragma unroll
                for (int r = 0; r < 4; ++r) {
                    int lr = ii * 16 + quad * 4 + r;      // local row within 32-row pass
                    float v = acc[i][j][r] + bv[j];
                    v = (v > 0.f) ? v : (__expf(v) - 1.0f);   // ELU(alpha=1), fast exp
                    Fls[lr * FLS_W + col] = v;
                }
            }
        }
        __syncthreads();
#pragma unroll
        for (int q = 0; q < 4; ++q) {                     // 32 rows x 256 cols, float4
            int f4 = q * 512 + t;
            int lr = f4 >> 6, c4 = f4 & 63;
            int grow = m0 + p * 32 + lr;
            if (grow < NN)
                __builtin_nontemporal_store(*(const f32x4*)&Fls[lr * FLS_W + c4 * 4],
                                            (f32x4*)(C + (size_t)grow * 256 + c4 * 4));
        }
    }
}

// ---------------------------------- launcher ----------------------------------
extern "C" void kernel_launch(void* const* d_in, const int* in_sizes, int n_in,
                              void* d_out, int out_size, void* d_ws, size_t ws_size,
                              hipStream_t stream) {
    const float* x    = (const float*)d_in[0];
    const int*   nbr  = (const int*)d_in[1];
    const float* R    = (const float*)d_in[2];
    const float* Ws   = (const float*)d_in[3];
    const float* Wn   = (const float*)d_in[4];
    const float* bias = (const float*)d_in[5];
    float* out = (float*)d_out;

    // workspace layout (all 16B-aligned): ~38.5 MB
    char* ws = (char*)d_ws;
    unsigned short* xb  = (unsigned short*)(ws);              // 25,600,000 B (bf16, self)
    unsigned char*  xb8 = (unsigned char*)(ws + 25600000);    // 12,800,000 B (fp8, gather)
    unsigned short* Bbf = (unsigned short*)(ws + 38400000);   //    131,072 B

    // 3133 blocks: 0..7 = weight MFMA GEMM (8 CUs); 8..3132 = x cast (3125*512*8 = 12.8M)
    hipLaunchKernelGGL(k_prep,  dim3(3133), dim3(512), 0, stream, x, R, Ws, Wn, xb, xb8, Bbf);
    hipLaunchKernelGGL(k_fused, dim3(1563), dim3(512), 0, stream, xb, xb8, nbr, Bbf, bias, out);
}